// Round 2
// baseline (157.497 us; speedup 1.0000x reference)
//
#include <hip/hip_runtime.h>
#include <hip/hip_cooperative_groups.h>

namespace cg = cooperative_groups;

// MixtureRouting: y[b,d,m] = sum_p x[b,d,p] * coef[b,p,m]
//   lh[b,p,m]  = pi[b,m] * prod_i( sig[b,i,m] / (PI*((mu[b,i,p]-mu[b,i,m])^2 + sig[b,i,m]^2)) )
//   coef[p,m]  = lh[p,m] / rowsum[p]
// R8 -> R9: 92.1us = 82.3us harness poison fills + 9.8us ours. Of the 9.8, ~7.5us is
// VALU evaluating lh TWICE (prep rowsum + gemm B-frags). Materializing lh in global
// costs its 33.5MB HBM writeback (R6) -- the only free channel is registers. In the
// gemm decomposition each lane's 128 lh values are produced AND consumed by the same
// lane, so: single cooperative kernel (256 blocks = 1/CU, co-resident), lh kept in
// 128 VGPRs across grid.sync:
//   Phase A: eval lh once (f32, in regs); per-wave LDS-transpose reduce ([16][33] pad,
//            <=2-way banks) -> block-partial rowsums to parts[b][mt][p]; plain x->bf16.
//   sync1;  Phase B: cooperative 64-way parts reduction -> rs[b][p] (2MB read ONCE).
//   sync2;  Phase D: invs=rcp(rs) in LDS; B-frags = v_cvt_pk_bf16_f32(lh*iv) pairs
//            (kills the 3-op manual RNE + repack); 12 MFMA/ks; epilogue as R8.
// LDS union: A: mus[0,32K)+rsT[32K,49.7K); B: bsum[0,2.1K); D: invs[32K,40K);
// epilogue: red[0,48K) (invs dead after the pre-epilogue barrier).

typedef float v4f __attribute__((ext_vector_type(4)));
typedef float f32x4 __attribute__((ext_vector_type(4)));
typedef short bf16x8 __attribute__((ext_vector_type(8)));

namespace {
constexpr int BB = 4;
constexpr int DD = 81;
constexpr int KK = 2048;
constexpr int MROWS = 96;                 // padded d-rows for MFMA (6 tiles of 16)
constexpr float INV_PI4 = 1.0f / 97.40909103400243f;

// ws layout (bytes) -- ~3.7 MB used
constexpr size_t OFF_XBF   = 0;                                     // ushort[B][96][K]
constexpr size_t OFF_PARTS = (size_t)BB * MROWS * KK * 2;           // float[B][64][K]
constexpr size_t OFF_RS    = OFF_PARTS + (size_t)BB * 64 * KK * 4;  // float[B][K]
}

__device__ __forceinline__ unsigned short f2bf(float f) {
    union { float f; unsigned int u; } v; v.f = f;
    unsigned int u = v.u;
    unsigned int r = (u + 0x7FFFu + ((u >> 16) & 1u)) >> 16;   // RNE
    return (unsigned short)r;
}

__global__ __launch_bounds__(512, 1) void fused_kernel(
    const float* __restrict__ x, const float* __restrict__ pi_,
    const float* __restrict__ mu, const float* __restrict__ sig,
    float* __restrict__ parts, float* __restrict__ rs,
    unsigned short* __restrict__ xbf, float* __restrict__ out) {
    __shared__ __align__(16) char smem[50176];
    v4f*  mus = (v4f*)smem;                                  // [2048] phase A (32 KB)
    float (*rsT)[16][33] = (float (*)[16][33])(smem + 32768);// [8][16][33] phase A
    float (*bsum)[33] = (float (*)[33])smem;                 // [16][33] phase B
    float* invs = (float*)(smem + 32768);                    // [2048] phase D
    f32x4 (*red)[6][64] = (f32x4 (*)[6][64])smem;            // [8][6][64] epilogue

    int t = threadIdx.x;
    int w = t >> 6, lane = t & 63;
    int r = lane & 15, q = lane >> 4;
    int bid = blockIdx.x;
    int b  = bid >> 6;
    int mt = bid & 63;
    int m0 = mt * 32;

    const float* mub = mu  + (size_t)b * 4 * KK;
    const float* sgb = sig + (size_t)b * 4 * KK;

    // ---- Phase A ----------------------------------------------------------
    // stage mu[b] transposed: mus[p] = {mu0[p], mu1[p], mu2[p], mu3[p]}
    for (int i = t; i < KK; i += 512)
        mus[i] = (v4f){mub[i], mub[KK + i], mub[2 * KK + i], mub[3 * KK + i]};

    // per-lane m-side constants for the two 16-col tiles
    int mA = m0 + r, mB = m0 + 16 + r;
    v4f mmA = {mub[mA], mub[KK + mA], mub[2 * KK + mA], mub[3 * KK + mA]};
    v4f sgA = {sgb[mA], sgb[KK + mA], sgb[2 * KK + mA], sgb[3 * KK + mA]};
    v4f s2A = sgA * sgA;
    float cA = pi_[(size_t)b * KK + mA] * ((sgA.x * sgA.y) * (sgA.z * sgA.w)) * INV_PI4;
    v4f mmB = {mub[mB], mub[KK + mB], mub[2 * KK + mB], mub[3 * KK + mB]};
    v4f sgB = {sgb[mB], sgb[KK + mB], sgb[2 * KK + mB], sgb[3 * KK + mB]};
    v4f s2B = sgB * sgB;
    float cB = pi_[(size_t)b * KK + mB] * ((sgB.x * sgB.y) * (sgB.z * sgB.w)) * INV_PI4;

    // plain x -> bf16 pad/convert (no rowsum dependency now; inv goes on B side).
    // 786432 elems / 256 blocks = 3072 each; same-b contiguous slice (3072*64 = 96*2048).
    {
        const float* xb = x + (size_t)b * DD * KK;
        unsigned short* xo = xbf + (size_t)b * MROWS * KK;
        int rembase = (bid & 63) * 3072;
#pragma unroll
        for (int k = 0; k < 6; ++k) {
            int rem = rembase + k * 512 + t;
            int d   = rem >> 11;
            int pp  = rem & 2047;
            float v = (d < DD) ? xb[(size_t)d * KK + pp] : 0.f;
            xo[rem] = f2bf(v);
        }
    }
    __syncthreads();

    // evaluate lh ONCE, keep f32 in registers; emit block-partial rowsums
    float lh0[8][8], lh1[8][8];
    int pw = w * 256;
    int pl = lane & 31, h = lane >> 5;
#pragma unroll
    for (int ks = 0; ks < 8; ++ks) {
        int pb = pw + ks * 32 + q * 8;
#pragma unroll
        for (int j = 0; j < 8; ++j) {
            v4f mp = mus[pb + j];
            v4f d0 = mp - mmA;
            v4f q0 = d0 * d0 + s2A;
            float den0 = (q0.x * q0.y) * (q0.z * q0.w);
            float l0 = cA * __builtin_amdgcn_rcpf(den0);
            v4f d1 = mp - mmB;
            v4f q1 = d1 * d1 + s2B;
            float den1 = (q1.x * q1.y) * (q1.z * q1.w);
            float l1 = cB * __builtin_amdgcn_rcpf(den1);
            lh0[ks][j] = l0;
            lh1[ks][j] = l1;
            rsT[w][r][q * 8 + j] = l0 + l1;          // per-wave tile, <=2-way banks
        }
        // wave-local column reduce: sum 16 r-rows for each of 32 p (same-wave LDS,
        // compiler inserts lgkmcnt; all 64 lanes' writes drain together)
        float s = 0.f;
#pragma unroll
        for (int k = 0; k < 8; ++k) s += rsT[w][h * 8 + k][pl];
        s += __shfl_xor(s, 32);
        if (h == 0)
            parts[((size_t)(b * 64 + mt)) * KK + pw + ks * 32 + pl] = s;
    }

    cg::this_grid().sync();

    // ---- Phase B: rs[b][p] = sum over 64 mt-parts (each (b,p) slot summed ONCE) ----
    {
        int ps = t & 31;
        int g  = t >> 5;                  // 0..15
        int slot = bid * 32 + ps;         // 0..8191, same b2 across the block's 32 slots
        int b2 = slot >> 11, p2 = slot & 2047;
        float s = 0.f;
#pragma unroll
        for (int i = 0; i < 4; ++i)
            s += parts[((size_t)(b2 * 64 + g * 4 + i)) * KK + p2];
        bsum[g][ps] = s;
        __syncthreads();
        if (t < 32) {
            float tot = 0.f;
#pragma unroll
            for (int g2 = 0; g2 < 16; ++g2) tot += bsum[g2][t];
            rs[(size_t)b2 * KK + p2] = tot;   // t<32 -> ps==t, b2/p2 valid
        }
    }

    cg::this_grid().sync();

    // ---- Phase D: invs stage, B-frags = cvt_pk(lh*iv), MFMA ----
    {
        const float* rsb = rs + (size_t)b * KK;
        for (int i = t; i < KK; i += 512)
            invs[i] = __builtin_amdgcn_rcpf(rsb[i]);
    }
    __syncthreads();

    const unsigned short* Abase = xbf + ((size_t)(b * MROWS + r)) * KK;
    f32x4 acc0[6], acc1[6];
#pragma unroll
    for (int i = 0; i < 6; ++i) { acc0[i] = (f32x4)0.f; acc1[i] = (f32x4)0.f; }

#pragma unroll
    for (int ks = 0; ks < 8; ++ks) {
        int pb = pw + ks * 32 + q * 8;
        f32x4 iv0 = *(const f32x4*)&invs[pb];
        f32x4 iv1 = *(const f32x4*)&invs[pb + 4];
        float iv[8] = {iv0.x, iv0.y, iv0.z, iv0.w, iv1.x, iv1.y, iv1.z, iv1.w};
        union { int i4[4]; bf16x8 v; } u0, u1;
#pragma unroll
        for (int d2 = 0; d2 < 4; ++d2) {
            float a0 = lh0[ks][2 * d2]     * iv[2 * d2];
            float a1 = lh0[ks][2 * d2 + 1] * iv[2 * d2 + 1];
            float b0 = lh1[ks][2 * d2]     * iv[2 * d2];
            float b1 = lh1[ks][2 * d2 + 1] * iv[2 * d2 + 1];
            asm("v_cvt_pk_bf16_f32 %0, %1, %2" : "=v"(u0.i4[d2]) : "v"(a0), "v"(a1));
            asm("v_cvt_pk_bf16_f32 %0, %1, %2" : "=v"(u1.i4[d2]) : "v"(b0), "v"(b1));
        }
        bf16x8 Af[6];
#pragma unroll
        for (int Mt = 0; Mt < 6; ++Mt)
            Af[Mt] = *(const bf16x8*)(Abase + (size_t)Mt * 16 * KK + pb);
#pragma unroll
        for (int Mt = 0; Mt < 6; ++Mt) {
            acc0[Mt] = __builtin_amdgcn_mfma_f32_16x16x32_bf16(Af[Mt], u0.v, acc0[Mt], 0, 0, 0);
            acc1[Mt] = __builtin_amdgcn_mfma_f32_16x16x32_bf16(Af[Mt], u1.v, acc1[Mt], 0, 0, 0);
        }
    }

    // ---- epilogue: two passes over 48KB cross-wave reduce buffer (reuses smem) ----
    int col = t & 15;
    int dr  = t >> 4;                    // 0..31
#pragma unroll
    for (int nt = 0; nt < 2; ++nt) {
        __syncthreads();                 // nt=0: all waves done reading invs
#pragma unroll
        for (int Mt = 0; Mt < 6; ++Mt)
            red[w][Mt][lane] = (nt == 0) ? acc0[Mt] : acc1[Mt];
        __syncthreads();
#pragma unroll
        for (int k = 0; k < 3; ++k) {
            int d = dr + 32 * k;         // 0..95
            if (d < DD) {
                int Mt  = d >> 4;
                int row = d & 15;
                int l   = (row >> 2) * 16 + col;
                int j   = row & 3;
                float s = 0.f;
#pragma unroll
                for (int ww = 0; ww < 8; ++ww) s += red[ww][Mt][l][j];
                out[((size_t)(b * DD + d)) * KK + m0 + nt * 16 + col] = s;
            }
        }
    }
}

extern "C" void kernel_launch(void* const* d_in, const int* in_sizes, int n_in,
                              void* d_out, int out_size, void* d_ws, size_t ws_size,
                              hipStream_t stream) {
    const float* x   = (const float*)d_in[0];
    const float* pi_ = (const float*)d_in[1];
    const float* mu  = (const float*)d_in[2];
    const float* sig = (const float*)d_in[3];
    float* out = (float*)d_out;

    unsigned short* xbf = (unsigned short*)((char*)d_ws + OFF_XBF);
    float* parts        = (float*)((char*)d_ws + OFF_PARTS);
    float* rs           = (float*)((char*)d_ws + OFF_RS);

    void* args[] = {(void*)&x, (void*)&pi_, (void*)&mu, (void*)&sig,
                    (void*)&parts, (void*)&rs, (void*)&xbf, (void*)&out};
    hipLaunchCooperativeKernel(reinterpret_cast<void*>(fused_kernel),
                               dim3(256), dim3(512), args, 0, stream);
}

// Round 3
// 87.999 us; speedup vs baseline: 1.7898x; 1.7898x over previous
//
#include <hip/hip_runtime.h>

// MixtureRouting: y[b,d,m] = sum_p x[b,d,p] * coef[b,p,m]
//   lh[b,p,m]  = pi[b,m] * prod_i( sig[b,i,m] / (PI*((mu[b,i,p]-mu[b,i,m])^2 + sig[b,i,m]^2)) )
//   coef[p,m]  = lh[p,m] / rowsum[p]
// R9 -> R10: R9's cooperative single-kernel (lh in regs across grid.sync) REGRESSED
// 92->157us: fused_kernel ran 85us at 8% VALU / 112 VGPR -- the 128-value cross-sync
// register payload spilled and the device-scope grid.sync stalled ~90% of the time.
// Refuted; reverted to the verified R8 two-kernel structure (92.08us = 82.3us harness
// poison fills + ~9.8us ours). R10 attacks the conversion tax instead: the manual
// 3-op RNE f2bf + pack, paid 16.8M times in gemm B-frags and 0.8M in xbf, becomes
// v_cvt_pk_bf16_f32 (1 instr / 2 values, same RNE -> bit-identical output).

typedef float v4f __attribute__((ext_vector_type(4)));
typedef float f32x4 __attribute__((ext_vector_type(4)));
typedef float f32x2 __attribute__((ext_vector_type(2)));
typedef short bf16x8 __attribute__((ext_vector_type(8)));

namespace {
constexpr int BB = 4;
constexpr int DD = 81;
constexpr int KK = 2048;
constexpr int MROWS = 96;                 // padded d-rows for MFMA (6 tiles of 16)
constexpr float INV_PI4 = 1.0f / 97.40909103400243f;

// ws layout (bytes) -- only 1.8 MB used
constexpr size_t OFF_XBF = 0;                                     // ushort[B][96][K]
constexpr size_t OFF_RSP = (size_t)BB * MROWS * KK * 2;           // float[B][8][K]
}

// ---------------------------------------------------------------------------
// prep: grid = B * 32 p-chunks * 8 m-slices = 1024 blocks, 256 threads.
// Part 1 (rowsum): rowsumPart[b][ms][p0+lane] = sum over 256 m of lh[p,m].
// Part 2 (xbf, fused): pure pad/convert x -> bf16 via pairwise v_cvt_pk_bf16_f32;
//   384 pairs per block (1024 blocks * 768 elems = 4*96*2048 exactly; same b).
// ---------------------------------------------------------------------------
__global__ __launch_bounds__(256) void prep_kernel(const float* __restrict__ x,
                                                   const float* __restrict__ pi_,
                                                   const float* __restrict__ mu,
                                                   const float* __restrict__ sig,
                                                   float* __restrict__ rowsumPart,
                                                   unsigned short* __restrict__ xbf) {
    __shared__ v4f   mush[256];
    __shared__ v4f   s2sh[256];
    __shared__ float csh[256];
    __shared__ float red[4][64];

    int blk = blockIdx.x;
    int b   = blk >> 8;
    int pc  = (blk & 255) >> 3;          // 0..31
    int ms  = blk & 7;                   // 0..7
    int p0  = pc * 64;
    int m0  = ms * 256;
    int t   = threadIdx.x;
    int lane = t & 63, w = t >> 6;

    const float* mub = mu  + (size_t)b * 4 * KK;
    const float* sgb = sig + (size_t)b * 4 * KK;
    const float* pib = pi_ + (size_t)b * KK;

    // stage m-side constants (thread t -> m0+t)
    {
        int m = m0 + t;
        v4f mm = {mub[m], mub[KK + m], mub[2 * KK + m], mub[3 * KK + m]};
        v4f sg = {sgb[m], sgb[KK + m], sgb[2 * KK + m], sgb[3 * KK + m]};
        mush[t] = mm;
        s2sh[t] = sg * sg;
        csh[t]  = pib[m] * ((sg.x * sg.y) * (sg.z * sg.w)) * INV_PI4;
    }
    // per-lane p-side constants
    int p = p0 + lane;
    v4f mp = {mub[p], mub[KK + p], mub[2 * KK + p], mub[3 * KK + p]};

    // fused xbf convert (independent of LDS staging; overlaps the barrier wait).
    // 384 bf16-pairs per block; pairs never cross a d-row (2048 even).
    {
        int prbase = (blk & 255) * 384;
        const float* xb = x + (size_t)b * DD * KK;
        unsigned int* xo = (unsigned int*)(xbf + (size_t)b * MROWS * KK);
#pragma unroll
        for (int k = 0; k < 2; ++k) {
            int idx = k * 256 + t;
            if (idx < 384) {
                int pr  = prbase + idx;
                int rem = pr * 2;
                int d   = rem >> 11;           // /2048
                int pp  = rem & 2047;
                f32x2 v = {0.f, 0.f};
                if (d < DD) v = *(const f32x2*)(xb + (size_t)d * KK + pp);
                unsigned int u;
                asm("v_cvt_pk_bf16_f32 %0, %1, %2" : "=v"(u) : "v"(v.x), "v"(v.y));
                xo[pr] = u;
            }
        }
    }
    __syncthreads();

    float sum = 0.f;
#pragma unroll 4
    for (int i = 0; i < 64; ++i) {
        int mi = w * 64 + i;                       // local m (this wave's quarter)
        v4f d = mp - mush[mi];
        v4f q = d * d + s2sh[mi];
        float den = (q.x * q.y) * (q.z * q.w);
        sum += csh[mi] * __builtin_amdgcn_rcpf(den);
    }

    red[w][lane] = sum;
    __syncthreads();
    if (t < 64)
        rowsumPart[((size_t)(b * 8 + ms)) * KK + p0 + t] =
            red[0][t] + red[1][t] + red[2][t] + red[3][t];
}

// ---------------------------------------------------------------------------
// gemm (fused coef): grid (64, B), 512 threads = 8 waves. Block = (b, 32-col m-tile),
// full K=2048; wave w owns p-slice [w*256, w*256+256).
// Per ks-step: lane (r,q) COMPUTES B-fragments coef[p=pb..pb+7][m] in registers for
// TWO 16-col tiles (m = m0+r and m0+16+r), sharing the mus/invs LDS reads and the
// 6 A-frag loads (xbf, L2-resident) -> 12x v_mfma_f32_16x16x32_bf16.
// B-frag f32->bf16 via v_cvt_pk_bf16_f32 (1 instr / pair, RNE -- replaces 3-op manual
// RNE + repack). A[m=lane&15][k=quad*8+j]; B[n=lane&15][k=quad*8+j]; D col=lane&15,
// row=quad*4+reg. LDS: 32KB mus + 8KB invs in K-loop; reused as 48KB reduce buffer.
// ---------------------------------------------------------------------------
__global__ __launch_bounds__(512) void gemm_kernel(const float* __restrict__ pi_,
                                                   const float* __restrict__ mu,
                                                   const float* __restrict__ sig,
                                                   const float* __restrict__ rowsumPart,
                                                   const unsigned short* __restrict__ xbf,
                                                   float* __restrict__ out) {
    __shared__ __align__(16) char smem[49152];          // 48 KB
    v4f*   mus  = (v4f*)smem;                           // [2048] (32 KB)
    float* invs = (float*)(smem + 32768);               // [2048] (8 KB)
    f32x4 (*red)[6][64] = (f32x4 (*)[6][64])smem;       // [8][6][64] after barrier (48 KB)

    int t = threadIdx.x;
    int w = t >> 6, lane = t & 63;
    int r = lane & 15, q = lane >> 4;
    int b  = blockIdx.y;
    int m0 = blockIdx.x * 32;

    const float* mub = mu  + (size_t)b * 4 * KK;
    const float* sgb = sig + (size_t)b * 4 * KK;
    const float* rspb = rowsumPart + (size_t)b * 8 * KK;

    // stage mu[b] transposed: mus[p] = {mu0[p], mu1[p], mu2[p], mu3[p]}
    for (int i = t; i < KK; i += 512)
        mus[i] = (v4f){mub[i], mub[KK + i], mub[2 * KK + i], mub[3 * KK + i]};
    // stage invrow[p] = 1 / sum_s rowsumPart[s][p]
    for (int i = t; i < KK; i += 512) {
        float s = 0.f;
#pragma unroll
        for (int sidx = 0; sidx < 8; ++sidx) s += rspb[(size_t)sidx * KK + i];
        invs[i] = __builtin_amdgcn_rcpf(s);
    }

    // per-lane m-side constants for the two 16-col tiles
    int mA = m0 + r, mB = m0 + 16 + r;
    v4f mmA = {mub[mA], mub[KK + mA], mub[2 * KK + mA], mub[3 * KK + mA]};
    v4f sgA = {sgb[mA], sgb[KK + mA], sgb[2 * KK + mA], sgb[3 * KK + mA]};
    v4f s2A = sgA * sgA;
    float cA = pi_[(size_t)b * KK + mA] * ((sgA.x * sgA.y) * (sgA.z * sgA.w)) * INV_PI4;
    v4f mmB = {mub[mB], mub[KK + mB], mub[2 * KK + mB], mub[3 * KK + mB]};
    v4f sgB = {sgb[mB], sgb[KK + mB], sgb[2 * KK + mB], sgb[3 * KK + mB]};
    v4f s2B = sgB * sgB;
    float cB = pi_[(size_t)b * KK + mB] * ((sgB.x * sgB.y) * (sgB.z * sgB.w)) * INV_PI4;

    const unsigned short* Abase = xbf + ((size_t)(b * MROWS + r)) * KK;

    f32x4 acc0[6], acc1[6];
#pragma unroll
    for (int i = 0; i < 6; ++i) { acc0[i] = (f32x4)0.f; acc1[i] = (f32x4)0.f; }

    __syncthreads();

    int pw = w * 256;
#pragma unroll
    for (int ks = 0; ks < 8; ++ks) {
        int pb = pw + ks * 32 + q * 8;
        // build B fragments in registers: coef = (c*iv)*rcp(den), packed pairwise
        union { int i4[4]; bf16x8 v; } u0, u1;
#pragma unroll
        for (int jp = 0; jp < 4; ++jp) {
            int j0 = 2 * jp, j1 = 2 * jp + 1;
            v4f mp0 = mus[pb + j0];
            v4f mp1 = mus[pb + j1];
            float iv0 = invs[pb + j0];
            float iv1 = invs[pb + j1];
            v4f dA0 = mp0 - mmA, dA1 = mp1 - mmA;
            v4f qA0 = dA0 * dA0 + s2A, qA1 = dA1 * dA1 + s2A;
            float a0 = (cA * iv0) * __builtin_amdgcn_rcpf((qA0.x * qA0.y) * (qA0.z * qA0.w));
            float a1 = (cA * iv1) * __builtin_amdgcn_rcpf((qA1.x * qA1.y) * (qA1.z * qA1.w));
            v4f dB0 = mp0 - mmB, dB1 = mp1 - mmB;
            v4f qB0 = dB0 * dB0 + s2B, qB1 = dB1 * dB1 + s2B;
            float b0 = (cB * iv0) * __builtin_amdgcn_rcpf((qB0.x * qB0.y) * (qB0.z * qB0.w));
            float b1 = (cB * iv1) * __builtin_amdgcn_rcpf((qB1.x * qB1.y) * (qB1.z * qB1.w));
            asm("v_cvt_pk_bf16_f32 %0, %1, %2" : "=v"(u0.i4[jp]) : "v"(a0), "v"(a1));
            asm("v_cvt_pk_bf16_f32 %0, %1, %2" : "=v"(u1.i4[jp]) : "v"(b0), "v"(b1));
        }
        bf16x8 Af[6];
#pragma unroll
        for (int Mt = 0; Mt < 6; ++Mt)
            Af[Mt] = *(const bf16x8*)(Abase + (size_t)Mt * 16 * KK + pb);
#pragma unroll
        for (int Mt = 0; Mt < 6; ++Mt) {
            acc0[Mt] = __builtin_amdgcn_mfma_f32_16x16x32_bf16(Af[Mt], u0.v, acc0[Mt], 0, 0, 0);
            acc1[Mt] = __builtin_amdgcn_mfma_f32_16x16x32_bf16(Af[Mt], u1.v, acc1[Mt], 0, 0, 0);
        }
    }

    // epilogue: two passes over the 48KB cross-wave reduce buffer (reuses mus/invs)
    int col = t & 15;
    int dr  = t >> 4;                    // 0..31
#pragma unroll
    for (int nt = 0; nt < 2; ++nt) {
        __syncthreads();                 // nt=0: waves done reading mus/invs
                                         // nt=1: waves done reading red pass 0
#pragma unroll
        for (int Mt = 0; Mt < 6; ++Mt)
            red[w][Mt][lane] = (nt == 0) ? acc0[Mt] : acc1[Mt];
        __syncthreads();
        // 1536 outputs (96 rows x 16 cols), 512 threads -> 3 each; skip d >= 81.
#pragma unroll
        for (int k = 0; k < 3; ++k) {
            int d = dr + 32 * k;         // 0..95
            if (d < DD) {
                int Mt  = d >> 4;
                int row = d & 15;
                int l   = (row >> 2) * 16 + col;
                int j   = row & 3;
                float s = 0.f;
#pragma unroll
                for (int ww = 0; ww < 8; ++ww) s += red[ww][Mt][l][j];
                out[((size_t)(b * DD + d)) * KK + m0 + nt * 16 + col] = s;
            }
        }
    }
}

extern "C" void kernel_launch(void* const* d_in, const int* in_sizes, int n_in,
                              void* d_out, int out_size, void* d_ws, size_t ws_size,
                              hipStream_t stream) {
    const float* x   = (const float*)d_in[0];
    const float* pi_ = (const float*)d_in[1];
    const float* mu  = (const float*)d_in[2];
    const float* sig = (const float*)d_in[3];
    float* out = (float*)d_out;

    unsigned short* xbf = (unsigned short*)((char*)d_ws + OFF_XBF);
    float* rowsumPart   = (float*)((char*)d_ws + OFF_RSP);

    prep_kernel<<<1024, 256, 0, stream>>>(x, pi_, mu, sig, rowsumPart, xbf);
    dim3 gg(KK / 32, BB);
    gemm_kernel<<<gg, 512, 0, stream>>>(pi_, mu, sig, rowsumPart, xbf, out);
}